// Round 9
// baseline (150.442 us; speedup 1.0000x reference)
//
#include <hip/hip_runtime.h>
#include <hip/hip_bf16.h>
#include <math.h>

// Problem dims
#define BB 2
#define LL 2048
#define DD 768
#define HH 12
#define EE 32
#define RR 57
#define NN 20
#define PP 248
#define MM 256          // P padded to 256 for MFMA tiles
#define KS 8            // K-split in context GEMM
#define KCH (LL / KS)   // 256

// ws layout (float offsets)
#define ENT_EMB_OFF 0                          // f32 B*E*D
#define A16_OFF   (BB * EE * DD)               // bf16 [B][MM][LL] (unnormalized q)
#define A16_F     (BB * MM * LL / 2)
#define CPART_OFF (A16_OFF + A16_F)            // f32 [KS][B][MM][DD]
#define CPART_F   (KS * BB * MM * DD)
#define CNT_OFF   (CPART_OFF + CPART_F)        // 16 ints: completion counters [b][mtile]

// kP grid roles
#define NQBLK (BB * 256)          // 512 q blocks (8-l chunks)
#define NEBLK (EE * BB)           // 64 ent_emb blocks
#define ASTRIDE 388               // att_s row stride (floats): 16B-aligned rows

// kGS grid roles
#define NGBLK 768                 // GEMM blocks (4 mtiles x 12 ntiles x 8 ks x 2 b)
#define NPT2 124                  // score pair-tiles of 2
#define NSBLK (NPT2 * BB * 2)     // 496 score blocks (x2 row-groups)

typedef __attribute__((ext_vector_type(8))) short bf16x8;
typedef __attribute__((ext_vector_type(4))) float f32x4;

__device__ __forceinline__ unsigned short f2bf(float f) {
    __hip_bfloat16 h = __float2bfloat16(f);
    return __builtin_bit_cast(unsigned short, h);
}
__device__ __forceinline__ float bf2f(unsigned short u) {
    unsigned int x = ((unsigned int)u) << 16;
    return __builtin_bit_cast(float, x);
}
__device__ __forceinline__ void pair_so(int p, int& s, int& o) {
    s = p / 31;
    int r = p - s * 31;
    o = (r < s) ? r : r + 1;
}
__device__ __forceinline__ float dot4(float4 a, float4 b) {
    return a.x * b.x + a.y * b.y + a.z * b.z + a.w * b.w;
}

// ===== Kernel P: role Q (att gather -> q rows, 8-l chunks), role E (ent_emb + cnt zero) =====
__global__ __launch_bounds__(256) void kP(const float* __restrict__ seq,
                                          const float* __restrict__ att,
                                          const int* __restrict__ spans,
                                          float* __restrict__ ws) {
    __shared__ __align__(16) float att_s[8][ASTRIDE];
    __shared__ int sp_s[EE];
    int bid = blockIdx.x;
    int t = threadIdx.x;

    if (bid < NQBLK) {
        int b = bid >> 8, l0 = (bid & 255) * 8;
        if (t < EE) sp_s[t] = spans[b * EE + t];
        __syncthreads();
        // 384 (e,h) rows x 2 segments of 4 l; average the 4 w-rows inline
        for (int i = t; i < EE * HH * 2; i += 256) {
            int seg = i & 1, eh = i >> 1;
            int e = eh / HH, h = eh - e * HH;
            const float* base = att + ((size_t)(b * HH + h) * LL + sp_s[e]) * LL + l0 + seg * 4;
            float4 v0 = *(const float4*)base;
            float4 v1 = *(const float4*)(base + LL);
            float4 v2 = *(const float4*)(base + 2 * LL);
            float4 v3 = *(const float4*)(base + 3 * LL);
            att_s[seg * 4 + 0][eh] = 0.25f * (v0.x + v1.x + v2.x + v3.x);
            att_s[seg * 4 + 1][eh] = 0.25f * (v0.y + v1.y + v2.y + v3.y);
            att_s[seg * 4 + 2][eh] = 0.25f * (v0.z + v1.z + v2.z + v3.z);
            att_s[seg * 4 + 3][eh] = 0.25f * (v0.w + v1.w + v2.w + v3.w);
        }
        __syncthreads();
        int p = t, s, o;
        pair_so(p, s, o);          // pads p>=248 -> s=8, o<=7: valid indices
        float q[8];
        #pragma unroll
        for (int l = 0; l < 8; ++l) {
            // h-vectorized: 12 h = 3 float4 per entity (16B-aligned: s*12*4B % 16 == 0)
            float4 a0 = *(const float4*)&att_s[l][s * HH];
            float4 a1 = *(const float4*)&att_s[l][s * HH + 4];
            float4 a2 = *(const float4*)&att_s[l][s * HH + 8];
            float4 b0 = *(const float4*)&att_s[l][o * HH];
            float4 b1 = *(const float4*)&att_s[l][o * HH + 4];
            float4 b2 = *(const float4*)&att_s[l][o * HH + 8];
            q[l] = dot4(a0, b0) + dot4(a1, b1) + dot4(a2, b2);
        }
        unsigned short* A16 = (unsigned short*)(ws + A16_OFF) + (size_t)(b * MM + p) * LL + l0;
        #pragma unroll
        for (int i = 0; i < 2; ++i) {
            ushort4 ov = make_ushort4(f2bf(q[i * 4 + 0]), f2bf(q[i * 4 + 1]),
                                      f2bf(q[i * 4 + 2]), f2bf(q[i * 4 + 3]));
            *(ushort4*)(A16 + i * 4) = ov;
        }
    } else {
        int bx = bid - NQBLK;
        int e = bx & 31, b = bx >> 5;
        if (bx == 0 && t < 16) ((int*)(ws + CNT_OFF))[t] = 0;   // zero counters
        int st = spans[b * EE + e];
        float* ee = ws + ENT_EMB_OFF + (size_t)(b * EE + e) * DD;
        const float* srow = seq + (size_t)(b * LL + st) * DD;
        for (int d = t; d < DD; d += 256) {
            ee[d] = 0.25f * (srow[d] + srow[DD + d] + srow[2 * DD + d] + srow[3 * DD + d]);
        }
    }
}

// ===== Kernel GS: role G (context GEMM + signal), role S (qsum -> spin -> score) =====
__global__ __launch_bounds__(256, 2) void kGS(const float* __restrict__ seq,
                                              const float* __restrict__ rel,
                                              const float* __restrict__ nota,
                                              float* __restrict__ ws,
                                              float* __restrict__ out) {
    __shared__ __align__(16) short As[64][40];
    __shared__ __align__(16) short Bs[64][40];
    __shared__ float red_s[4][2];
    __shared__ float qs_s[2];
    __shared__ float nota_s[2][NN];
    int bid = blockIdx.x;
    int t = threadIdx.x;
    int w = t >> 6, lane = t & 63;
    int* cnt = (int*)(ws + CNT_OFF);

    if (bid < NGBLK) {
        // ---- role G: cpart[ks][b][m][n] = sum_k A[m][k]*seq[k][n] (bf16 MFMA) ----
        int m0 = (bid & 3) * 64;
        int n0 = ((bid >> 2) % 12) * 64;
        int z = bid / 48;
        int ks = z & 7, b = z >> 3;
        const unsigned short* A =
            (const unsigned short*)(ws + A16_OFF) + (size_t)b * MM * LL;
        int row = t >> 2, seg = t & 3;          // A staging
        int bl = t >> 3, bd = t & 7;            // B staging: 32 l-rows x 8 d-segs
        int wr = w >> 1, wc = w & 1;
        int fr = lane & 15, kb = lane >> 4;
        f32x4 acc[2][2] = {};
        int k0c = ks * KCH;
        for (int st = 0; st < KCH / 32; ++st) {
            int kk = k0c + st * 32;
            *(uint4*)&As[row][seg * 8] =
                *(const uint4*)(A + (size_t)(m0 + row) * LL + kk + seg * 8);
            {
                const float* sp2 = seq + (size_t)(b * LL + kk + bl) * DD + n0 + bd * 8;
                float4 u0 = *(const float4*)sp2;
                float4 u1 = *(const float4*)(sp2 + 4);
                unsigned short bv[8] = {f2bf(u0.x), f2bf(u0.y), f2bf(u0.z), f2bf(u0.w),
                                        f2bf(u1.x), f2bf(u1.y), f2bf(u1.z), f2bf(u1.w)};
                #pragma unroll
                for (int i = 0; i < 8; ++i) {
                    int k = (i + bd) & 7;       // stagger: 16-way -> 2-way bank conflict
                    Bs[bd * 8 + k][bl] = (short)bv[k];
                }
            }
            __syncthreads();
            bf16x8 af[2], bfr[2];
            #pragma unroll
            for (int i = 0; i < 2; ++i) af[i] = *(bf16x8*)&As[wr * 32 + i * 16 + fr][kb * 8];
            #pragma unroll
            for (int j = 0; j < 2; ++j) bfr[j] = *(bf16x8*)&Bs[wc * 32 + j * 16 + fr][kb * 8];
            #pragma unroll
            for (int i = 0; i < 2; ++i)
                #pragma unroll
                for (int j = 0; j < 2; ++j)
                    acc[i][j] = __builtin_amdgcn_mfma_f32_16x16x32_bf16(
                        af[i], bfr[j], acc[i][j], 0, 0, 0);
            __syncthreads();
        }
        float* cp = ws + CPART_OFF + (size_t)((ks * BB + b) * MM) * DD;
        #pragma unroll
        for (int i = 0; i < 2; ++i)
            #pragma unroll
            for (int j = 0; j < 2; ++j)
                #pragma unroll
                for (int r = 0; r < 4; ++r) {
                    int gm = m0 + wr * 32 + i * 16 + kb * 4 + r;
                    int gn = n0 + wc * 32 + j * 16 + fr;
                    cp[(size_t)gm * DD + gn] = acc[i][j][r];
                }
        __syncthreads();   // all block stores drained (vmcnt before barrier)
        if (t == 0) {
            __threadfence();                         // wb L2 -> agent-visible
            atomicAdd(&cnt[b * 4 + (m0 >> 6)], 1);   // signal (device scope)
        }
    } else {
        // ---- role S: 2 pairs; phase0 qsum, spin on GEMM mtile, then score ----
        int sid = bid - NGBLK;
        int gz = sid / (NPT2 * BB);
        int rem = sid - gz * (NPT2 * BB);
        int b = rem / NPT2;
        int pt2 = rem - b * NPT2;
        int p0 = pt2 * 2, mt = p0 >> 6;
        // phase 0: qsum per pair (independent of GEMM)
        {
            const unsigned short* A16 =
                (const unsigned short*)(ws + A16_OFF) + (size_t)(b * MM + p0) * LL;
            #pragma unroll
            for (int j = 0; j < 2; ++j) {
                ushort4 u0 = *(const ushort4*)(A16 + (size_t)j * LL + t * 8);
                ushort4 u1 = *(const ushort4*)(A16 + (size_t)j * LL + t * 8 + 4);
                float v = bf2f(u0.x) + bf2f(u0.y) + bf2f(u0.z) + bf2f(u0.w)
                        + bf2f(u1.x) + bf2f(u1.y) + bf2f(u1.z) + bf2f(u1.w);
                #pragma unroll
                for (int off = 32; off > 0; off >>= 1) v += __shfl_xor(v, off, 64);
                if (lane == 0) red_s[w][j] = v;
            }
            __syncthreads();
            if (t < 2)
                qs_s[t] = 1.0f / (red_s[0][t] + red_s[1][t] + red_s[2][t] + red_s[3][t]);
        }
        // spin until all 96 GEMM blocks (12 ntiles x 8 ks) of this (b, mtile) signaled
        if (t == 0) {
            while (__hip_atomic_load(&cnt[b * 4 + mt], __ATOMIC_RELAXED,
                                     __HIP_MEMORY_SCOPE_AGENT) < 96)
                __builtin_amdgcn_s_sleep(16);
        }
        __syncthreads();
        __threadfence();   // inv L2 -> see remote-XCD cpart
        // phase 1: per-lane emb fragments for 2 pairs
        float4 er[2][9];
        #pragma unroll
        for (int j = 0; j < 2; ++j) {
            int p = p0 + j;
            int s, o;
            pair_so(p, s, o);
            const float4* es = (const float4*)(ws + ENT_EMB_OFF + (size_t)(b * EE + s) * DD);
            const float4* eo = (const float4*)(ws + ENT_EMB_OFF + (size_t)(b * EE + o) * DD);
            float qs = qs_s[j];
            #pragma unroll
            for (int i4 = 0; i4 < 3; ++i4) er[j][i4] = es[i4 * 64 + lane];
            #pragma unroll
            for (int i4 = 0; i4 < 3; ++i4) er[j][3 + i4] = eo[i4 * 64 + lane];
            #pragma unroll
            for (int i4 = 0; i4 < 3; ++i4) {
                float4 sum = make_float4(0.f, 0.f, 0.f, 0.f);
                #pragma unroll
                for (int ls = 0; ls < KS; ++ls) {
                    const float4* cp = (const float4*)(ws + CPART_OFF +
                                       (size_t)((ls * BB + b) * MM + p) * DD);
                    float4 v = cp[i4 * 64 + lane];
                    sum.x += v.x; sum.y += v.y; sum.z += v.z; sum.w += v.w;
                }
                er[j][6 + i4] = make_float4(sum.x * qs, sum.y * qs, sum.z * qs, sum.w * qs);
            }
        }
        // phase 2: rows [lo,hi) for this group; 2 code rows per iteration
        int lo = (gz == 0) ? 0 : 39;
        int hi = (gz == 0) ? 39 : (RR + NN);
        for (int base = lo + w * 2; base < hi; base += 8) {
            int r1 = base + 1;
            bool has1 = (r1 < hi);
            const float4* code0 = (base < RR)
                ? (const float4*)(rel + (size_t)base * 3 * DD)
                : (const float4*)(nota + (size_t)(base - RR) * 3 * DD);
            const float4* code1 = has1
                ? ((r1 < RR) ? (const float4*)(rel + (size_t)r1 * 3 * DD)
                             : (const float4*)(nota + (size_t)(r1 - RR) * 3 * DD))
                : code0;
            float acc0[2] = {0.f, 0.f};
            float acc1[2] = {0.f, 0.f};
            #pragma unroll
            for (int i4 = 0; i4 < 9; ++i4) {
                float4 c0 = code0[i4 * 64 + lane];
                float4 c1 = code1[i4 * 64 + lane];
                #pragma unroll
                for (int j = 0; j < 2; ++j) {
                    acc0[j] += dot4(c0, er[j][i4]);
                    acc1[j] += dot4(c1, er[j][i4]);
                }
            }
            #pragma unroll
            for (int j = 0; j < 2; ++j) {
                float v0 = acc0[j], v1 = acc1[j];
                #pragma unroll
                for (int off = 32; off > 0; off >>= 1) {
                    v0 += __shfl_xor(v0, off, 64);
                    v1 += __shfl_xor(v1, off, 64);
                }
                if (lane == 0) {
                    int p = p0 + j;
                    if (base < RR) out[(size_t)(b * PP + p) * (RR + 1) + 1 + base] = v0;
                    else nota_s[j][base - RR] = v0;
                    if (has1) {
                        if (r1 < RR) out[(size_t)(b * PP + p) * (RR + 1) + 1 + r1] = v1;
                        else nota_s[j][r1 - RR] = v1;
                    }
                }
            }
        }
        __syncthreads();
        if (gz == 1 && t < 2) {
            float m = -INFINITY;
            #pragma unroll
            for (int n = 0; n < NN; ++n) m = fmaxf(m, nota_s[t][n]);
            out[(size_t)(b * PP + p0 + t) * (RR + 1)] = m;
        }
    }
}

extern "C" void kernel_launch(void* const* d_in, const int* in_sizes, int n_in,
                              void* d_out, int out_size, void* d_ws, size_t ws_size,
                              hipStream_t stream) {
    const float* seq   = (const float*)d_in[0];
    const float* att   = (const float*)d_in[1];
    const float* rel   = (const float*)d_in[2];
    const float* nota  = (const float*)d_in[3];
    const int*   spans = (const int*)d_in[4];
    float* ws  = (float*)d_ws;
    float* out = (float*)d_out;

    kP<<<NQBLK + NEBLK, 256, 0, stream>>>(seq, att, spans, ws);
    kGS<<<NGBLK + NSBLK, 256, 0, stream>>>(seq, rel, nota, ws, out);
}

// Round 10
// 108.044 us; speedup vs baseline: 1.3924x; 1.3924x over previous
//
#include <hip/hip_runtime.h>
#include <hip/hip_bf16.h>
#include <math.h>

// Problem dims
#define BB 2
#define LL 2048
#define DD 768
#define HH 12
#define EE 32
#define RR 57
#define NN 20
#define PP 248
#define MM 256          // P padded to 256 for MFMA tiles
#define KS 8            // K-split in context GEMM
#define KCH (LL / KS)   // 256

// ws layout (float offsets)
#define ENT_EMB_OFF 0                          // f32 B*E*D
#define A16_OFF   (BB * EE * DD)               // bf16 [B][MM][LL] (unnormalized q)
#define A16_F     (BB * MM * LL / 2)
#define CPART_OFF (A16_OFF + A16_F)            // f32 [KS][B][MM][DD]
#define CPART_F   (KS * BB * MM * DD)
#define CNT_OFF   (CPART_OFF + CPART_F)        // 16 ints: completion counters [b][mtile]

// kP grid roles
#define NQBLK (BB * 256)          // 512 q blocks (8-l chunks)
#define NEBLK (EE * BB)           // 64 ent_emb blocks
#define ASTRIDE 388               // att_s row stride (floats)

// kGS grid roles
#define NGBLK 768                 // GEMM blocks (4 mtiles x 12 ntiles x 8 ks x 2 b)
#define PT4 4
#define NSBLK 124                 // score blocks: 62 ptiles x 2 b, 4 pairs, full rows

typedef __attribute__((ext_vector_type(8))) short bf16x8;
typedef __attribute__((ext_vector_type(4))) float f32x4;

__device__ __forceinline__ unsigned short f2bf(float f) {
    __hip_bfloat16 h = __float2bfloat16(f);
    return __builtin_bit_cast(unsigned short, h);
}
__device__ __forceinline__ float bf2f(unsigned short u) {
    unsigned int x = ((unsigned int)u) << 16;
    return __builtin_bit_cast(float, x);
}
__device__ __forceinline__ void pair_so(int p, int& s, int& o) {
    s = p / 31;
    int r = p - s * 31;
    o = (r < s) ? r : r + 1;
}
__device__ __forceinline__ float dot4(float4 a, float4 b) {
    return a.x * b.x + a.y * b.y + a.z * b.z + a.w * b.w;
}

// ===== Kernel P: role Q (att gather -> q rows, 8-l chunks), role E (ent_emb + cnt zero) =====
__global__ __launch_bounds__(256) void kP(const float* __restrict__ seq,
                                          const float* __restrict__ att,
                                          const int* __restrict__ spans,
                                          float* __restrict__ ws) {
    __shared__ __align__(16) float att_s[8][ASTRIDE];
    __shared__ int sp_s[EE];
    int bid = blockIdx.x;
    int t = threadIdx.x;

    if (bid < NQBLK) {
        int b = bid >> 8, l0 = (bid & 255) * 8;
        if (t < EE) sp_s[t] = spans[b * EE + t];
        __syncthreads();
        for (int i = t; i < EE * HH * 2; i += 256) {
            int seg = i & 1, eh = i >> 1;
            int e = eh / HH, h = eh - e * HH;
            const float* base = att + ((size_t)(b * HH + h) * LL + sp_s[e]) * LL + l0 + seg * 4;
            float4 v0 = *(const float4*)base;
            float4 v1 = *(const float4*)(base + LL);
            float4 v2 = *(const float4*)(base + 2 * LL);
            float4 v3 = *(const float4*)(base + 3 * LL);
            att_s[seg * 4 + 0][eh] = 0.25f * (v0.x + v1.x + v2.x + v3.x);
            att_s[seg * 4 + 1][eh] = 0.25f * (v0.y + v1.y + v2.y + v3.y);
            att_s[seg * 4 + 2][eh] = 0.25f * (v0.z + v1.z + v2.z + v3.z);
            att_s[seg * 4 + 3][eh] = 0.25f * (v0.w + v1.w + v2.w + v3.w);
        }
        __syncthreads();
        int p = t, s, o;
        pair_so(p, s, o);          // pads p>=248 -> s=8, o<=7: valid indices
        float q[8];
        #pragma unroll
        for (int l = 0; l < 8; ++l) {
            float4 a0 = *(const float4*)&att_s[l][s * HH];
            float4 a1 = *(const float4*)&att_s[l][s * HH + 4];
            float4 a2 = *(const float4*)&att_s[l][s * HH + 8];
            float4 b0 = *(const float4*)&att_s[l][o * HH];
            float4 b1 = *(const float4*)&att_s[l][o * HH + 4];
            float4 b2 = *(const float4*)&att_s[l][o * HH + 8];
            q[l] = dot4(a0, b0) + dot4(a1, b1) + dot4(a2, b2);
        }
        unsigned short* A16 = (unsigned short*)(ws + A16_OFF) + (size_t)(b * MM + p) * LL + l0;
        #pragma unroll
        for (int i = 0; i < 2; ++i) {
            ushort4 ov = make_ushort4(f2bf(q[i * 4 + 0]), f2bf(q[i * 4 + 1]),
                                      f2bf(q[i * 4 + 2]), f2bf(q[i * 4 + 3]));
            *(ushort4*)(A16 + i * 4) = ov;
        }
    } else {
        int bx = bid - NQBLK;
        int e = bx & 31, b = bx >> 5;
        if (bx == 0 && t < 16) ((int*)(ws + CNT_OFF))[t] = 0;   // zero counters
        int st = spans[b * EE + e];
        float* ee = ws + ENT_EMB_OFF + (size_t)(b * EE + e) * DD;
        const float* srow = seq + (size_t)(b * LL + st) * DD;
        for (int d = t; d < DD; d += 256) {
            ee[d] = 0.25f * (srow[d] + srow[DD + d] + srow[2 * DD + d] + srow[3 * DD + d]);
        }
    }
}

// ===== Kernel GS: bids [0,768) GEMM + signal; bids [768,892) score (spin-gated) =====
__global__ __launch_bounds__(256) void kGS(const float* __restrict__ seq,
                                           const float* __restrict__ rel,
                                           const float* __restrict__ nota,
                                           float* __restrict__ ws,
                                           float* __restrict__ out) {
    __shared__ __align__(16) short As[64][40];
    __shared__ __align__(16) short Bs[64][40];
    __shared__ float red_s[4][PT4];
    __shared__ float qs_s[PT4];
    __shared__ float nota_s[PT4][NN];
    int bid = blockIdx.x;
    int t = threadIdx.x;
    int w = t >> 6, lane = t & 63;
    int* cnt = (int*)(ws + CNT_OFF);

    if (bid < NGBLK) {
        // ---- role G: cpart[ks][b][m][n] = sum_k A[m][k]*seq[k][n] (bf16 MFMA) ----
        int m0 = (bid & 3) * 64;
        int n0 = ((bid >> 2) % 12) * 64;
        int z = bid / 48;
        int ks = z & 7, b = z >> 3;
        const unsigned short* A =
            (const unsigned short*)(ws + A16_OFF) + (size_t)b * MM * LL;
        int row = t >> 2, seg = t & 3;          // A staging
        int bl = t >> 3, bd = t & 7;            // B staging: 32 l-rows x 8 d-segs
        int wr = w >> 1, wc = w & 1;
        int fr = lane & 15, kb = lane >> 4;
        f32x4 acc[2][2] = {};
        int k0c = ks * KCH;
        for (int st = 0; st < KCH / 32; ++st) {
            int kk = k0c + st * 32;
            *(uint4*)&As[row][seg * 8] =
                *(const uint4*)(A + (size_t)(m0 + row) * LL + kk + seg * 8);
            {
                const float* sp2 = seq + (size_t)(b * LL + kk + bl) * DD + n0 + bd * 8;
                float4 u0 = *(const float4*)sp2;
                float4 u1 = *(const float4*)(sp2 + 4);
                unsigned short bv[8] = {f2bf(u0.x), f2bf(u0.y), f2bf(u0.z), f2bf(u0.w),
                                        f2bf(u1.x), f2bf(u1.y), f2bf(u1.z), f2bf(u1.w)};
                #pragma unroll
                for (int i = 0; i < 8; ++i) {
                    int k = (i + bd) & 7;       // stagger: 16-way -> 2-way bank conflict
                    Bs[bd * 8 + k][bl] = (short)bv[k];
                }
            }
            __syncthreads();
            bf16x8 af[2], bfr[2];
            #pragma unroll
            for (int i = 0; i < 2; ++i) af[i] = *(bf16x8*)&As[wr * 32 + i * 16 + fr][kb * 8];
            #pragma unroll
            for (int j = 0; j < 2; ++j) bfr[j] = *(bf16x8*)&Bs[wc * 32 + j * 16 + fr][kb * 8];
            #pragma unroll
            for (int i = 0; i < 2; ++i)
                #pragma unroll
                for (int j = 0; j < 2; ++j)
                    acc[i][j] = __builtin_amdgcn_mfma_f32_16x16x32_bf16(
                        af[i], bfr[j], acc[i][j], 0, 0, 0);
            __syncthreads();
        }
        float* cp = ws + CPART_OFF + (size_t)((ks * BB + b) * MM) * DD;
        #pragma unroll
        for (int i = 0; i < 2; ++i)
            #pragma unroll
            for (int j = 0; j < 2; ++j)
                #pragma unroll
                for (int r = 0; r < 4; ++r) {
                    int gm = m0 + wr * 32 + i * 16 + kb * 4 + r;
                    int gn = n0 + wc * 32 + j * 16 + fr;
                    cp[(size_t)gm * DD + gn] = acc[i][j][r];
                }
        __syncthreads();   // all block stores drained (vmcnt before barrier)
        if (t == 0) {
            __threadfence();                         // wb L2 -> agent-visible
            atomicAdd(&cnt[b * 4 + (m0 >> 6)], 1);   // signal (device scope)
        }
    } else {
        // ---- role S: 4 pairs, full 77 rows; qsum -> spin on mtile -> score ----
        int sid = bid - NGBLK;          // 0..123
        int b = sid / 62;
        int pt = sid - b * 62;
        int p0 = pt * PT4, mt = p0 >> 6;
        // phase 0: qsum per pair (independent of GEMM)
        {
            const unsigned short* A16 =
                (const unsigned short*)(ws + A16_OFF) + (size_t)(b * MM + p0) * LL;
            #pragma unroll
            for (int j = 0; j < PT4; ++j) {
                ushort4 u0 = *(const ushort4*)(A16 + (size_t)j * LL + t * 8);
                ushort4 u1 = *(const ushort4*)(A16 + (size_t)j * LL + t * 8 + 4);
                float v = bf2f(u0.x) + bf2f(u0.y) + bf2f(u0.z) + bf2f(u0.w)
                        + bf2f(u1.x) + bf2f(u1.y) + bf2f(u1.z) + bf2f(u1.w);
                #pragma unroll
                for (int off = 32; off > 0; off >>= 1) v += __shfl_xor(v, off, 64);
                if (lane == 0) red_s[w][j] = v;
            }
            __syncthreads();
            if (t < PT4)
                qs_s[t] = 1.0f / (red_s[0][t] + red_s[1][t] + red_s[2][t] + red_s[3][t]);
        }
        // spin until all 96 GEMM blocks (12 ntiles x 8 ks) of this (b, mtile) signaled
        if (t == 0) {
            while (__hip_atomic_load(&cnt[b * 4 + mt], __ATOMIC_RELAXED,
                                     __HIP_MEMORY_SCOPE_AGENT) < 96)
                __builtin_amdgcn_s_sleep(16);
        }
        __syncthreads();
        __threadfence();   // inv L2 -> see remote-XCD cpart
        // phase 1: per-lane emb fragments for 4 pairs
        float4 er[PT4][9];
        #pragma unroll
        for (int j = 0; j < PT4; ++j) {
            int p = p0 + j;
            int s, o;
            pair_so(p, s, o);
            const float4* es = (const float4*)(ws + ENT_EMB_OFF + (size_t)(b * EE + s) * DD);
            const float4* eo = (const float4*)(ws + ENT_EMB_OFF + (size_t)(b * EE + o) * DD);
            float qs = qs_s[j];
            #pragma unroll
            for (int i4 = 0; i4 < 3; ++i4) er[j][i4] = es[i4 * 64 + lane];
            #pragma unroll
            for (int i4 = 0; i4 < 3; ++i4) er[j][3 + i4] = eo[i4 * 64 + lane];
            #pragma unroll
            for (int i4 = 0; i4 < 3; ++i4) {
                float4 sum = make_float4(0.f, 0.f, 0.f, 0.f);
                #pragma unroll
                for (int ls = 0; ls < KS; ++ls) {
                    const float4* cp = (const float4*)(ws + CPART_OFF +
                                       (size_t)((ls * BB + b) * MM + p) * DD);
                    float4 v = cp[i4 * 64 + lane];
                    sum.x += v.x; sum.y += v.y; sum.z += v.z; sum.w += v.w;
                }
                er[j][6 + i4] = make_float4(sum.x * qs, sum.y * qs, sum.z * qs, sum.w * qs);
            }
        }
        // phase 2: all 77 rows, 2 per iteration per wave
        for (int base = w * 2; base < RR + NN; base += 8) {
            int r1 = base + 1;
            bool has1 = (r1 < RR + NN);
            const float4* code0 = (base < RR)
                ? (const float4*)(rel + (size_t)base * 3 * DD)
                : (const float4*)(nota + (size_t)(base - RR) * 3 * DD);
            const float4* code1 = has1
                ? ((r1 < RR) ? (const float4*)(rel + (size_t)r1 * 3 * DD)
                             : (const float4*)(nota + (size_t)(r1 - RR) * 3 * DD))
                : code0;
            float acc0[PT4] = {0.f, 0.f, 0.f, 0.f};
            float acc1[PT4] = {0.f, 0.f, 0.f, 0.f};
            #pragma unroll
            for (int i4 = 0; i4 < 9; ++i4) {
                float4 c0 = code0[i4 * 64 + lane];
                float4 c1 = code1[i4 * 64 + lane];
                #pragma unroll
                for (int j = 0; j < PT4; ++j) {
                    acc0[j] += dot4(c0, er[j][i4]);
                    acc1[j] += dot4(c1, er[j][i4]);
                }
            }
            #pragma unroll
            for (int j = 0; j < PT4; ++j) {
                float v0 = acc0[j], v1 = acc1[j];
                #pragma unroll
                for (int off = 32; off > 0; off >>= 1) {
                    v0 += __shfl_xor(v0, off, 64);
                    v1 += __shfl_xor(v1, off, 64);
                }
                if (lane == 0) {
                    int p = p0 + j;
                    if (base < RR) out[(size_t)(b * PP + p) * (RR + 1) + 1 + base] = v0;
                    else nota_s[j][base - RR] = v0;
                    if (has1) {
                        if (r1 < RR) out[(size_t)(b * PP + p) * (RR + 1) + 1 + r1] = v1;
                        else nota_s[j][r1 - RR] = v1;
                    }
                }
            }
        }
        __syncthreads();
        if (t < PT4) {
            float m = -INFINITY;
            #pragma unroll
            for (int n = 0; n < NN; ++n) m = fmaxf(m, nota_s[t][n]);
            out[(size_t)(b * PP + p0 + t) * (RR + 1)] = m;
        }
    }
}

extern "C" void kernel_launch(void* const* d_in, const int* in_sizes, int n_in,
                              void* d_out, int out_size, void* d_ws, size_t ws_size,
                              hipStream_t stream) {
    const float* seq   = (const float*)d_in[0];
    const float* att   = (const float*)d_in[1];
    const float* rel   = (const float*)d_in[2];
    const float* nota  = (const float*)d_in[3];
    const int*   spans = (const int*)d_in[4];
    float* ws  = (float*)d_ws;
    float* out = (float*)d_out;

    kP<<<NQBLK + NEBLK, 256, 0, stream>>>(seq, att, spans, ws);
    kGS<<<NGBLK + NSBLK, 256, 0, stream>>>(seq, rel, nota, ws, out);
}

// Round 11
// 47.584 us; speedup vs baseline: 3.1616x; 2.2706x over previous
//
#include <hip/hip_runtime.h>
#include <hip/hip_bf16.h>
#include <math.h>

// Problem dims
#define BB 2
#define LL 2048
#define DD 768
#define HH 12
#define EE 32
#define RR 57
#define NN 20
#define PP 248
#define MM 256          // P padded to 256 for MFMA tiles
#define KS 8            // K-split in context GEMM
#define KCH (LL / KS)   // 256

// ws layout (float offsets)
#define ENT_EMB_OFF 0                          // f32 B*E*D
#define A16_OFF   (BB * EE * DD)               // bf16 [B][MM][LL] (unnormalized q)
#define A16_F     (BB * MM * LL / 2)
#define CPART_OFF (A16_OFF + A16_F)            // f32 [KS][B][MM][DD]

#define PT4 4
#define NPT4 62

// kP grid roles
#define NQBLK (BB * 256)          // 512 q blocks (8-l chunks), XCD-swizzled
#define NEBLK (EE * BB)           // 64 ent_emb blocks
#define ASTRIDE 388               // att_s row stride (floats)

typedef __attribute__((ext_vector_type(8))) short bf16x8;
typedef __attribute__((ext_vector_type(4))) float f32x4;

__device__ __forceinline__ unsigned short f2bf(float f) {
    __hip_bfloat16 h = __float2bfloat16(f);
    return __builtin_bit_cast(unsigned short, h);
}
__device__ __forceinline__ float bf2f(unsigned short u) {
    unsigned int x = ((unsigned int)u) << 16;
    return __builtin_bit_cast(float, x);
}
__device__ __forceinline__ void pair_so(int p, int& s, int& o) {
    s = p / 31;
    int r = p - s * 31;
    o = (r < s) ? r : r + 1;
}
__device__ __forceinline__ float dot4(float4 a, float4 b) {
    return a.x * b.x + a.y * b.y + a.z * b.z + a.w * b.w;
}

// ===== Kernel P: role Q (att gather -> q rows, 8-l chunks, XCD-swizzled), role E =====
__global__ __launch_bounds__(256) void kP(const float* __restrict__ seq,
                                          const float* __restrict__ att,
                                          const int* __restrict__ spans,
                                          float* __restrict__ ws) {
    __shared__ __align__(16) float att_s[8][ASTRIDE];
    __shared__ int sp_s[EE];
    int bid = blockIdx.x;
    int t = threadIdx.x;

    if (bid < NQBLK) {
        // XCD-aware swizzle: blocks on the same XCD (bid%8) take CONTIGUOUS
        // l-chunks, so the 4x 32B pieces of each 128B att line stay in one L2.
        int xcd = bid & 7, i = bid >> 3;
        int chunk = xcd * (NQBLK / 8) + i;       // 0..511
        int b = chunk >> 8, l0 = (chunk & 255) * 8;
        if (t < EE) sp_s[t] = spans[b * EE + t];
        __syncthreads();
        // 384 (e,h) rows x 2 segments of 4 l; average the 4 w-rows inline
        for (int i2 = t; i2 < EE * HH * 2; i2 += 256) {
            int seg = i2 & 1, eh = i2 >> 1;
            int e = eh / HH, h = eh - e * HH;
            const float* base = att + ((size_t)(b * HH + h) * LL + sp_s[e]) * LL + l0 + seg * 4;
            float4 v0 = *(const float4*)base;
            float4 v1 = *(const float4*)(base + LL);
            float4 v2 = *(const float4*)(base + 2 * LL);
            float4 v3 = *(const float4*)(base + 3 * LL);
            att_s[seg * 4 + 0][eh] = 0.25f * (v0.x + v1.x + v2.x + v3.x);
            att_s[seg * 4 + 1][eh] = 0.25f * (v0.y + v1.y + v2.y + v3.y);
            att_s[seg * 4 + 2][eh] = 0.25f * (v0.z + v1.z + v2.z + v3.z);
            att_s[seg * 4 + 3][eh] = 0.25f * (v0.w + v1.w + v2.w + v3.w);
        }
        __syncthreads();
        int p = t, s, o;
        pair_so(p, s, o);          // pads p>=248 -> s=8, o<=7: valid indices
        float q[8];
        #pragma unroll
        for (int l = 0; l < 8; ++l) {
            float4 a0 = *(const float4*)&att_s[l][s * HH];
            float4 a1 = *(const float4*)&att_s[l][s * HH + 4];
            float4 a2 = *(const float4*)&att_s[l][s * HH + 8];
            float4 b0 = *(const float4*)&att_s[l][o * HH];
            float4 b1 = *(const float4*)&att_s[l][o * HH + 4];
            float4 b2 = *(const float4*)&att_s[l][o * HH + 8];
            q[l] = dot4(a0, b0) + dot4(a1, b1) + dot4(a2, b2);
        }
        unsigned short* A16 = (unsigned short*)(ws + A16_OFF) + (size_t)(b * MM + p) * LL + l0;
        #pragma unroll
        for (int i2 = 0; i2 < 2; ++i2) {
            ushort4 ov = make_ushort4(f2bf(q[i2 * 4 + 0]), f2bf(q[i2 * 4 + 1]),
                                      f2bf(q[i2 * 4 + 2]), f2bf(q[i2 * 4 + 3]));
            *(ushort4*)(A16 + i2 * 4) = ov;
        }
    } else {
        int bx = bid - NQBLK;
        int e = bx & 31, b = bx >> 5;
        int st = spans[b * EE + e];
        float* ee = ws + ENT_EMB_OFF + (size_t)(b * EE + e) * DD;
        const float* srow = seq + (size_t)(b * LL + st) * DD;
        for (int d = t; d < DD; d += 256) {
            ee[d] = 0.25f * (srow[d] + srow[DD + d] + srow[2 * DD + d] + srow[3 * DD + d]);
        }
    }
}

// Kernel 3: cpart[ks][b][m][n] = sum_{k in split} A[m][k] * seq[k][n]  (bf16 MFMA)
// B-operand staged directly from f32 seq with fused transpose+cast.
__global__ __launch_bounds__(256) void k3_gemm(const float* __restrict__ seq,
                                               float* __restrict__ ws) {
    int m0 = blockIdx.x * 64, n0 = blockIdx.y * 64;
    int ks = blockIdx.z & (KS - 1), b = blockIdx.z >> 3;
    const unsigned short* A = (const unsigned short*)(ws + A16_OFF) + (size_t)b * MM * LL;
    __shared__ __align__(16) short As[64][40];
    __shared__ __align__(16) short Bs[64][40];
    int t = threadIdx.x;
    int row = t >> 2, seg = t & 3;          // A staging
    int bl = t >> 3, bd = t & 7;            // B staging: 32 l-rows x 8 d-segs
    int w = t >> 6, lane = t & 63;
    int wr = w >> 1, wc = w & 1;
    int fr = lane & 15, kb = lane >> 4;
    f32x4 acc[2][2] = {};
    int k0c = ks * KCH;
    for (int st = 0; st < KCH / 32; ++st) {
        int kk = k0c + st * 32;
        *(uint4*)&As[row][seg * 8] = *(const uint4*)(A + (size_t)(m0 + row) * LL + kk + seg * 8);
        {
            const float* sp2 = seq + (size_t)(b * LL + kk + bl) * DD + n0 + bd * 8;
            float4 u0 = *(const float4*)sp2;
            float4 u1 = *(const float4*)(sp2 + 4);
            unsigned short bv[8] = {f2bf(u0.x), f2bf(u0.y), f2bf(u0.z), f2bf(u0.w),
                                    f2bf(u1.x), f2bf(u1.y), f2bf(u1.z), f2bf(u1.w)};
            #pragma unroll
            for (int i = 0; i < 8; ++i) {
                int k = (i + bd) & 7;       // stagger: 16-way -> 2-way bank conflict
                Bs[bd * 8 + k][bl] = (short)bv[k];
            }
        }
        __syncthreads();
        bf16x8 af[2], bfr[2];
        #pragma unroll
        for (int i = 0; i < 2; ++i) af[i] = *(bf16x8*)&As[wr * 32 + i * 16 + fr][kb * 8];
        #pragma unroll
        for (int j = 0; j < 2; ++j) bfr[j] = *(bf16x8*)&Bs[wc * 32 + j * 16 + fr][kb * 8];
        #pragma unroll
        for (int i = 0; i < 2; ++i)
            #pragma unroll
            for (int j = 0; j < 2; ++j)
                acc[i][j] = __builtin_amdgcn_mfma_f32_16x16x32_bf16(af[i], bfr[j], acc[i][j], 0, 0, 0);
        __syncthreads();
    }
    float* cp = ws + CPART_OFF + (size_t)((ks * BB + b) * MM) * DD;
    #pragma unroll
    for (int i = 0; i < 2; ++i)
        #pragma unroll
        for (int j = 0; j < 2; ++j)
            #pragma unroll
            for (int r = 0; r < 4; ++r) {
                int gm = m0 + wr * 32 + i * 16 + kb * 4 + r;
                int gn = n0 + wc * 32 + j * 16 + fr;
                cp[(size_t)gm * DD + gn] = acc[i][j][r];
            }
}

// Kernel 4: qsum + register emb + scoring; rows split across 2 block-groups (z)
__global__ __launch_bounds__(256, 1) void k4_score(const float* __restrict__ rel,
                                                   const float* __restrict__ nota,
                                                   const float* __restrict__ ws,
                                                   float* __restrict__ out) {
    int pt = blockIdx.x, b = blockIdx.y, gz = blockIdx.z;
    int tid = threadIdx.x, w = tid >> 6, lane = tid & 63;
    __shared__ float red_s[4][PT4];
    __shared__ float qs_s[PT4];
    __shared__ float nota_s[PT4][NN];
    // phase 0: qsum per pair (from bf16 q rows)
    {
        const unsigned short* A16 =
            (const unsigned short*)(ws + A16_OFF) + (size_t)(b * MM + pt * PT4) * LL;
        #pragma unroll
        for (int j = 0; j < PT4; ++j) {
            ushort4 u0 = *(const ushort4*)(A16 + (size_t)j * LL + tid * 8);
            ushort4 u1 = *(const ushort4*)(A16 + (size_t)j * LL + tid * 8 + 4);
            float v = bf2f(u0.x) + bf2f(u0.y) + bf2f(u0.z) + bf2f(u0.w)
                    + bf2f(u1.x) + bf2f(u1.y) + bf2f(u1.z) + bf2f(u1.w);
            #pragma unroll
            for (int off = 32; off > 0; off >>= 1) v += __shfl_xor(v, off, 64);
            if (lane == 0) red_s[w][j] = v;
        }
        __syncthreads();
        if (tid < PT4)
            qs_s[tid] = 1.0f / (red_s[0][tid] + red_s[1][tid] + red_s[2][tid] + red_s[3][tid]);
        __syncthreads();
    }
    // phase 1: per-lane emb fragments for all 4 pairs
    float4 er[PT4][9];
    #pragma unroll
    for (int j = 0; j < PT4; ++j) {
        int p = pt * PT4 + j;
        int s, o;
        pair_so(p, s, o);
        const float4* es = (const float4*)(ws + ENT_EMB_OFF + (size_t)(b * EE + s) * DD);
        const float4* eo = (const float4*)(ws + ENT_EMB_OFF + (size_t)(b * EE + o) * DD);
        float qs = qs_s[j];
        #pragma unroll
        for (int i4 = 0; i4 < 3; ++i4) er[j][i4] = es[i4 * 64 + lane];
        #pragma unroll
        for (int i4 = 0; i4 < 3; ++i4) er[j][3 + i4] = eo[i4 * 64 + lane];
        #pragma unroll
        for (int i4 = 0; i4 < 3; ++i4) {
            float4 sum = make_float4(0.f, 0.f, 0.f, 0.f);
            #pragma unroll
            for (int ls = 0; ls < KS; ++ls) {
                const float4* cp = (const float4*)(ws + CPART_OFF +
                                   (size_t)((ls * BB + b) * MM + p) * DD);
                float4 v = cp[i4 * 64 + lane];
                sum.x += v.x; sum.y += v.y; sum.z += v.z; sum.w += v.w;
            }
            er[j][6 + i4] = make_float4(sum.x * qs, sum.y * qs, sum.z * qs, sum.w * qs);
        }
    }
    // phase 2: rows [lo,hi) for this group; 2 code rows per iteration
    int lo = (gz == 0) ? 0 : 39;
    int hi = (gz == 0) ? 39 : (RR + NN);
    for (int base = lo + w * 2; base < hi; base += 8) {
        int r1 = base + 1;
        bool has1 = (r1 < hi);
        const float4* code0 = (base < RR)
            ? (const float4*)(rel + (size_t)base * 3 * DD)
            : (const float4*)(nota + (size_t)(base - RR) * 3 * DD);
        const float4* code1 = has1
            ? ((r1 < RR) ? (const float4*)(rel + (size_t)r1 * 3 * DD)
                         : (const float4*)(nota + (size_t)(r1 - RR) * 3 * DD))
            : code0;
        float acc0[PT4] = {0.f, 0.f, 0.f, 0.f};
        float acc1[PT4] = {0.f, 0.f, 0.f, 0.f};
        #pragma unroll
        for (int i4 = 0; i4 < 9; ++i4) {
            float4 c0 = code0[i4 * 64 + lane];
            float4 c1 = code1[i4 * 64 + lane];
            #pragma unroll
            for (int j = 0; j < PT4; ++j) {
                acc0[j] += dot4(c0, er[j][i4]);
                acc1[j] += dot4(c1, er[j][i4]);
            }
        }
        #pragma unroll
        for (int j = 0; j < PT4; ++j) {
            float v0 = acc0[j], v1 = acc1[j];
            #pragma unroll
            for (int off = 32; off > 0; off >>= 1) {
                v0 += __shfl_xor(v0, off, 64);
                v1 += __shfl_xor(v1, off, 64);
            }
            if (lane == 0) {
                int p = pt * PT4 + j;
                if (base < RR) out[(size_t)(b * PP + p) * (RR + 1) + 1 + base] = v0;
                else nota_s[j][base - RR] = v0;
                if (has1) {
                    if (r1 < RR) out[(size_t)(b * PP + p) * (RR + 1) + 1 + r1] = v1;
                    else nota_s[j][r1 - RR] = v1;
                }
            }
        }
    }
    __syncthreads();
    if (gz == 1 && tid < PT4) {
        float m = -INFINITY;
        #pragma unroll
        for (int n = 0; n < NN; ++n) m = fmaxf(m, nota_s[tid][n]);
        out[(size_t)(b * PP + pt * PT4 + tid) * (RR + 1)] = m;
    }
}

extern "C" void kernel_launch(void* const* d_in, const int* in_sizes, int n_in,
                              void* d_out, int out_size, void* d_ws, size_t ws_size,
                              hipStream_t stream) {
    const float* seq   = (const float*)d_in[0];
    const float* att   = (const float*)d_in[1];
    const float* rel   = (const float*)d_in[2];
    const float* nota  = (const float*)d_in[3];
    const int*   spans = (const int*)d_in[4];
    float* ws  = (float*)d_ws;
    float* out = (float*)d_out;

    kP<<<NQBLK + NEBLK, 256, 0, stream>>>(seq, att, spans, ws);
    k3_gemm<<<dim3(MM / 64, DD / 64, KS * BB), 256, 0, stream>>>(seq, ws);
    k4_score<<<dim3(NPT4, BB, 2), 256, 0, stream>>>(rel, nota, ws, out);
}